// Round 1
// baseline (267.420 us; speedup 1.0000x reference)
//
#include <hip/hip_runtime.h>
#include <hip/hip_bf16.h>

#define HH 4096      // canvas side
#define KK 32        // box / tile side
#define OH 4065      // HH - KK + 1
#define NB 225       // output cols per band (256 input cols - 31)
#define BC 256       // input cols per block == threads
#define RCHUNK 32    // output rows per block (was 64; halved to feed 8 blocks/CU)
#define GR 8         // output rows per LDS group
#define NSUB (RCHUNK / GR)   // 4 groups

// Barrier that drains ONLY LDS (lgkmcnt). Global prefetch loads stay in
// flight across it — __syncthreads() would s_waitcnt vmcnt(0) and kill the
// software pipeline. asm memory clobbers stop compiler-level reordering.
__device__ __forceinline__ void barrier_lds_only() {
    asm volatile("" ::: "memory");
    __builtin_amdgcn_s_waitcnt(0xC07F);   // vmcnt(63) expcnt(7) lgkmcnt(0)
    __builtin_amdgcn_s_barrier();
    asm volatile("" ::: "memory");
}

// __launch_bounds__(256, 8): 8 waves/EU -> 8 blocks/CU target. This pins the
// allocator at <=64 VGPR (it lands at exactly 64 naturally). Per-CU caps all
// hit exactly: 8 x 20KB = 160KB LDS, 8 x 4 = 32 waves, 64 VGPR/wave.
__global__ __launch_bounds__(BC, 8) void som_fused(
    const float* __restrict__ img,   // 32x32
    const float* __restrict__ som,   // 4096x4096
    const float* __restrict__ var,   // 4096x4096
    float* __restrict__ out)         // 4065x4065
{
    __shared__ float simg[KK * KK];        // 4 KB
    __shared__ float ldsv[2][GR][BC];      // 16 KB (scan done in place)

    const int tid  = threadIdx.x;
    const int lane = tid & 63;
    const int wv   = tid >> 6;

    for (int i = tid; i < KK * KK; i += BC) simg[i] = img[i];
    __syncthreads();                       // once; full barrier is fine here

    const int c0   = blockIdx.x * NB;
    const int col  = c0 + tid;
    const int colc = col < HH ? col : HH - 1;   // clamp (last band only)
    const int jc   = col & (KK - 1);
    const int r0   = blockIdx.y * RCHUNK;       // multiple of 32
    const int maxoff = HH - 1 - r0;             // uniform row-offset clamp

    const float* sp = som + (size_t)r0 * HH + colc;
    const float* vp = var + (size_t)r0 * HH + colc;

    // ---- init vertical window: rows r0 .. r0+31 (exposed once per block) ----
    float ring[KK];
    float sum = 0.f;
#pragma unroll
    for (int t = 0; t < KK; ++t) {
        const float s  = sp[t * HH];              // t <= 31 <= maxoff always
        const float v  = vp[t * HH];
        const float im = simg[(t << 5) | jc];     // (r0+t)&31 == t (r0 % 32 == 0)
        const float e  = im - s;
        const float d  = e * e * __builtin_amdgcn_rcpf(v + 1e-8f);
        ring[t] = d;
        sum += d;
    }

    // ---- prefetch group 0 (rows r0+32 .. r0+39) into bank 0 ----
    // NOTE: with RCHUNK=32 the last chunk has maxoff=31 < 32, so this
    // initial prefetch must clamp too (clamped rows only feed rout >= OH).
    float pf_s[2][GR], pf_v[2][GR];
#pragma unroll
    for (int k = 0; k < GR; ++k) {
        int off = KK + k;
        off = off <= maxoff ? off : maxoff;
        pf_s[0][k] = sp[off * HH];
        pf_v[0][k] = vp[off * HH];
    }

#pragma unroll
    for (int sub = 0; sub < NSUB; ++sub) {
        const int buf = sub & 1;

        // ---- issue prefetch for group sub+1 into the other bank ----
        // (sub is a compile-time constant under unroll: the final dead
        //  prefetch is eliminated entirely, ~12% fewer load instructions)
        if (sub + 1 < NSUB) {
#pragma unroll
            for (int k = 0; k < GR; ++k) {
                int off = KK + (sub + 1) * GR + k;
                off = off <= maxoff ? off : maxoff; // clamped rows only feed rout>=OH
                pf_s[buf ^ 1][k] = sp[off * HH];
                pf_v[buf ^ 1][k] = vp[off * HH];
            }
        }

        // ---- phase A: emit GR column sums, slide window (branch-free) ----
#pragma unroll
        for (int k = 0; k < GR; ++k) {
            ldsv[buf][k][tid] = sum;            // vsum for row r0+sub*GR+k
            const float s  = pf_s[buf][k];
            const float v  = pf_v[buf][k];
            const float im = simg[(((sub * GR + k) & (KK - 1)) << 5) | jc]; // static offset
            const float e  = im - s;
            const float d  = e * e * __builtin_amdgcn_rcpf(v + 1e-8f);
            const int ri   = (sub * GR + k) & (KK - 1);   // static ring index
            sum += d - ring[ri];
            ring[ri] = d;
        }
        barrier_lds_only();

        // ---- phase B: in-place inclusive prefix scan, 2 rows per wave ----
#pragma unroll
        for (int rr = 0; rr < 2; ++rr) {
            const int k = 2 * wv + rr;
            float4 x = *(const float4*)&ldsv[buf][k][lane * 4];
            const float p0 = x.x;
            const float p1 = p0 + x.y;
            const float p2 = p1 + x.z;
            const float p3 = p2 + x.w;
            float sc = p3;
#pragma unroll
            for (int off = 1; off < 64; off <<= 1) {
                const float t = __shfl_up(sc, off, 64);
                sc += (lane >= off) ? t : 0.f;
            }
            const float excl = sc - p3;
            float4 o;
            o.x = p0 + excl; o.y = p1 + excl; o.z = p2 + excl; o.w = p3 + excl;
            *(float4*)&ldsv[buf][k][lane * 4] = o;
        }
        barrier_lds_only();

        // ---- phase C: horizontal window = P[c+31] - P[c-1], coalesced store ----
        if (tid < NB && col < OH) {
#pragma unroll
            for (int k = 0; k < GR; ++k) {
                const int rout = r0 + sub * GR + k;
                if (rout < OH) {
                    const float hi = ldsv[buf][k][tid + KK - 1];
                    const float lo = (tid > 0) ? ldsv[buf][k][tid - 1] : 0.f;
                    out[(size_t)rout * OH + col] = hi - lo;
                }
            }
        }
        // no barrier needed: next group writes the other ldsv bank; the two
        // barriers of group sub+1 order this phase C vs. phase A of sub+2.
    }
}

extern "C" void kernel_launch(void* const* d_in, const int* in_sizes, int n_in,
                              void* d_out, int out_size, void* d_ws, size_t ws_size,
                              hipStream_t stream) {
    (void)in_sizes; (void)n_in; (void)out_size; (void)d_ws; (void)ws_size;
    const float* img = (const float*)d_in[0];   // 32x32
    const float* som = (const float*)d_in[1];   // 4096x4096
    const float* var = (const float*)d_in[2];   // 4096x4096
    float* out = (float*)d_out;                 // 4065x4065

    dim3 blk(BC);
    dim3 grd((OH + NB - 1) / NB,                // 19 column bands
             (OH + RCHUNK - 1) / RCHUNK);       // 128 row chunks
    hipLaunchKernelGGL(som_fused, grd, blk, 0, stream, img, som, var, out);
}

// Round 2
// 201.442 us; speedup vs baseline: 1.3275x; 1.3275x over previous
//
#include <hip/hip_runtime.h>
#include <hip/hip_bf16.h>

#define HH 4096      // canvas side
#define KK 32        // box / tile side
#define OH 4065      // HH - KK + 1
#define NB 225       // output cols per band (256 input cols - 31)
#define BC 256       // input cols per block == threads
#define RCHUNK 32    // output rows per block (halved vs r0 to double grid supply)
#define GR 8         // output rows per LDS group
#define NSUB (RCHUNK / GR)   // 4 groups

// Barrier that drains ONLY LDS (lgkmcnt). Global prefetch loads stay in
// flight across it — __syncthreads() would s_waitcnt vmcnt(0) and kill the
// software pipeline. asm memory clobbers stop compiler-level reordering.
__device__ __forceinline__ void barrier_lds_only() {
    asm volatile("" ::: "memory");
    __builtin_amdgcn_s_waitcnt(0xC07F);   // vmcnt(63) expcnt(7) lgkmcnt(0)
    __builtin_amdgcn_s_barrier();
    asm volatile("" ::: "memory");
}

// __launch_bounds__(256, 4): R1 post-mortem — requesting 8 waves/EU forced
// VGPR=32 and spilled ring[]+pf[] to scratch (+155 MB writes). At (256,4)
// the allocator lands at exactly 64 VGPR, spill-free (proven in R0). R1 also
// showed residency tracks GRID SUPPLY (31%->66% when blocks/CU went
// 4.75->9.5), so the doubled grid alone buys the occupancy.
__global__ __launch_bounds__(BC, 4) void som_fused(
    const float* __restrict__ img,   // 32x32
    const float* __restrict__ som,   // 4096x4096
    const float* __restrict__ var,   // 4096x4096
    float* __restrict__ out)         // 4065x4065
{
    __shared__ float simg[KK * KK];        // 4 KB
    __shared__ float ldsv[2][GR][BC];      // 16 KB (scan done in place)

    const int tid  = threadIdx.x;
    const int lane = tid & 63;
    const int wv   = tid >> 6;

    for (int i = tid; i < KK * KK; i += BC) simg[i] = img[i];
    __syncthreads();                       // once; full barrier is fine here

    const int c0   = blockIdx.x * NB;
    const int col  = c0 + tid;
    const int colc = col < HH ? col : HH - 1;   // clamp (last band only)
    const int jc   = col & (KK - 1);
    const int r0   = blockIdx.y * RCHUNK;       // multiple of 32
    const int maxoff = HH - 1 - r0;             // uniform row-offset clamp

    const float* sp = som + (size_t)r0 * HH + colc;
    const float* vp = var + (size_t)r0 * HH + colc;

    // ---- init vertical window: rows r0 .. r0+31 (exposed once per block) ----
    float ring[KK];
    float sum = 0.f;
#pragma unroll
    for (int t = 0; t < KK; ++t) {
        const float s  = sp[t * HH];              // t <= 31 <= maxoff always
        const float v  = vp[t * HH];
        const float im = simg[(t << 5) | jc];     // (r0+t)&31 == t (r0 % 32 == 0)
        const float e  = im - s;
        const float d  = e * e * __builtin_amdgcn_rcpf(v + 1e-8f);
        ring[t] = d;
        sum += d;
    }

    // ---- prefetch group 0 (rows r0+32 .. r0+39) into bank 0 ----
    // NOTE: with RCHUNK=32 the last chunk has maxoff=31 < 32, so this
    // initial prefetch must clamp too (clamped rows only feed rout >= OH).
    float pf_s[2][GR], pf_v[2][GR];
#pragma unroll
    for (int k = 0; k < GR; ++k) {
        int off = KK + k;
        off = off <= maxoff ? off : maxoff;
        pf_s[0][k] = sp[off * HH];
        pf_v[0][k] = vp[off * HH];
    }

#pragma unroll
    for (int sub = 0; sub < NSUB; ++sub) {
        const int buf = sub & 1;

        // ---- issue prefetch for group sub+1 into the other bank ----
        // (sub is a compile-time constant under unroll: the final dead
        //  prefetch is eliminated entirely)
        if (sub + 1 < NSUB) {
#pragma unroll
            for (int k = 0; k < GR; ++k) {
                int off = KK + (sub + 1) * GR + k;
                off = off <= maxoff ? off : maxoff; // clamped rows only feed rout>=OH
                pf_s[buf ^ 1][k] = sp[off * HH];
                pf_v[buf ^ 1][k] = vp[off * HH];
            }
        }

        // ---- phase A: emit GR column sums, slide window (branch-free) ----
#pragma unroll
        for (int k = 0; k < GR; ++k) {
            ldsv[buf][k][tid] = sum;            // vsum for row r0+sub*GR+k
            const float s  = pf_s[buf][k];
            const float v  = pf_v[buf][k];
            const float im = simg[(((sub * GR + k) & (KK - 1)) << 5) | jc]; // static offset
            const float e  = im - s;
            const float d  = e * e * __builtin_amdgcn_rcpf(v + 1e-8f);
            const int ri   = (sub * GR + k) & (KK - 1);   // static ring index
            sum += d - ring[ri];
            ring[ri] = d;
        }
        barrier_lds_only();

        // ---- phase B: in-place inclusive prefix scan, 2 rows per wave ----
#pragma unroll
        for (int rr = 0; rr < 2; ++rr) {
            const int k = 2 * wv + rr;
            float4 x = *(const float4*)&ldsv[buf][k][lane * 4];
            const float p0 = x.x;
            const float p1 = p0 + x.y;
            const float p2 = p1 + x.z;
            const float p3 = p2 + x.w;
            float sc = p3;
#pragma unroll
            for (int off = 1; off < 64; off <<= 1) {
                const float t = __shfl_up(sc, off, 64);
                sc += (lane >= off) ? t : 0.f;
            }
            const float excl = sc - p3;
            float4 o;
            o.x = p0 + excl; o.y = p1 + excl; o.z = p2 + excl; o.w = p3 + excl;
            *(float4*)&ldsv[buf][k][lane * 4] = o;
        }
        barrier_lds_only();

        // ---- phase C: horizontal window = P[c+31] - P[c-1], coalesced store ----
        if (tid < NB && col < OH) {
#pragma unroll
            for (int k = 0; k < GR; ++k) {
                const int rout = r0 + sub * GR + k;
                if (rout < OH) {
                    const float hi = ldsv[buf][k][tid + KK - 1];
                    const float lo = (tid > 0) ? ldsv[buf][k][tid - 1] : 0.f;
                    out[(size_t)rout * OH + col] = hi - lo;
                }
            }
        }
        // no barrier needed: next group writes the other ldsv bank; the two
        // barriers of group sub+1 order this phase C vs. phase A of sub+2.
    }
}

extern "C" void kernel_launch(void* const* d_in, const int* in_sizes, int n_in,
                              void* d_out, int out_size, void* d_ws, size_t ws_size,
                              hipStream_t stream) {
    (void)in_sizes; (void)n_in; (void)out_size; (void)d_ws; (void)ws_size;
    const float* img = (const float*)d_in[0];   // 32x32
    const float* som = (const float*)d_in[1];   // 4096x4096
    const float* var = (const float*)d_in[2];   // 4096x4096
    float* out = (float*)d_out;                 // 4065x4065

    dim3 blk(BC);
    dim3 grd((OH + NB - 1) / NB,                // 19 column bands
             (OH + RCHUNK - 1) / RCHUNK);       // 128 row chunks
    hipLaunchKernelGGL(som_fused, grd, blk, 0, stream, img, som, var, out);
}